// Round 1
// baseline (272.889 us; speedup 1.0000x reference)
//
#include <hip/hip_runtime.h>

// PoolObj: ball-query (annulus) neighbor-count downsampling + gather.
// B=4, N=4096, C=3, D=64, K=N/2=2048.
// Output: concat( new_xyz [B,K,3], new_points [B,K,D] ) as float32.

#define BN 4
#define NPTS 4096
#define ND 64
#define KSEL (NPTS / 2)
#define R2 0.0025f   // RADIUS^2
#define M2 0.0004f   // MIN_RADIUS^2

// Kernel 1: per-point annulus neighbor counts.
// grid = B * (N/256) = 64 blocks, 256 threads. One batch's points in LDS.
__global__ __launch_bounds__(256) void pool_count_kernel(
        const float* __restrict__ xyz, int* __restrict__ counts) {
    __shared__ float4 pts[NPTS];   // 64 KB: (x, y, z, sq)
    const int b    = blockIdx.x >> 4;   // / (N/256)
    const int tile = blockIdx.x & 15;
    const float* base = xyz + (size_t)b * 3 * NPTS;

    for (int idx = threadIdx.x; idx < NPTS; idx += 256) {
        float x = base[idx];
        float y = base[NPTS + idx];
        float z = base[2 * NPTS + idx];
        // sq = (x*x + y*y) + z*z, no FMA contraction (match numpy rounding)
        float sq = __fadd_rn(__fadd_rn(__fmul_rn(x, x), __fmul_rn(y, y)),
                             __fmul_rn(z, z));
        pts[idx] = make_float4(x, y, z, sq);
    }
    __syncthreads();

    const int i = tile * 256 + threadIdx.x;
    const float4 me = pts[i];
    int cnt = 0;
    #pragma unroll 4
    for (int j = 0; j < NPTS; ++j) {
        float4 p = pts[j];
        // dot = (xi*xj + yi*yj) + zi*zj ; d2 = (sq_i + sq_j) - 2*dot
        float dot = __fadd_rn(__fadd_rn(__fmul_rn(me.x, p.x),
                                        __fmul_rn(me.y, p.y)),
                              __fmul_rn(me.z, p.z));
        float d2 = __fsub_rn(__fadd_rn(me.w, p.w), __fmul_rn(2.0f, dot));
        cnt += (d2 < R2 && d2 > M2) ? 1 : 0;
    }
    counts[b * NPTS + i] = cnt;
}

// Kernel 2: rank each point by (count desc, index asc); rank < K  => selected,
// output position = rank (replicates jax.lax.top_k stable tie-break exactly).
// grid = B * (N/256) = 64 blocks, 256 threads.
__global__ __launch_bounds__(256) void pool_rank_gather_kernel(
        const float* __restrict__ xyz, const float* __restrict__ points,
        const int* __restrict__ counts, float* __restrict__ out) {
    __shared__ int cnts[NPTS];   // 16 KB
    const int b    = blockIdx.x >> 4;
    const int tile = blockIdx.x & 15;
    const int* cbase = counts + b * NPTS;
    for (int idx = threadIdx.x; idx < NPTS; idx += 256) cnts[idx] = cbase[idx];
    __syncthreads();

    const int i  = tile * 256 + threadIdx.x;
    const int ci = cnts[i];
    int rank = 0;
    #pragma unroll 4
    for (int j = 0; j < NPTS; ++j) {
        int cj = cnts[j];
        rank += (cj > ci || (cj == ci && j < i)) ? 1 : 0;
    }

    if (rank < KSEL) {
        const float* xb = xyz + (size_t)b * 3 * NPTS;
        float* oxyz = out + ((size_t)b * KSEL + rank) * 3;
        oxyz[0] = xb[i];
        oxyz[1] = xb[NPTS + i];
        oxyz[2] = xb[2 * NPTS + i];

        const float* pb = points + (size_t)b * ND * NPTS + i;
        float* opts = out + (size_t)BN * KSEL * 3 + ((size_t)b * KSEL + rank) * ND;
        #pragma unroll
        for (int c = 0; c < ND; ++c) opts[c] = pb[(size_t)c * NPTS];
    }
}

extern "C" void kernel_launch(void* const* d_in, const int* in_sizes, int n_in,
                              void* d_out, int out_size, void* d_ws, size_t ws_size,
                              hipStream_t stream) {
    const float* xyz    = (const float*)d_in[0];   // [B, 3, N, 1]
    const float* points = (const float*)d_in[1];   // [B, D, N, 1]
    float* out = (float*)d_out;                    // [B*K*3] ++ [B*K*D]
    int* counts = (int*)d_ws;                      // B*N ints = 256 KB

    pool_count_kernel<<<BN * (NPTS / 256), 256, 0, stream>>>(xyz, counts);
    pool_rank_gather_kernel<<<BN * (NPTS / 256), 256, 0, stream>>>(
        xyz, points, counts, out);
}

// Round 2
// 91.791 us; speedup vs baseline: 2.9729x; 2.9729x over previous
//
#include <hip/hip_runtime.h>

// PoolObj: ball-query (annulus) neighbor-count downsampling + gather.
// B=4, N=4096, D=64, K=2048. Out = concat(new_xyz [B,K,3], new_points [B,K,D]).
//
// Structure (all accumulators integer -> deterministic under atomics):
//   prep    : pts4[b][i] = (x,y,z,sq), zero counts/ranks
//   count   : annulus neighbor counts, j-split across 32 chunks, atomicAdd
//   rank    : rank_i = #{j : key_j > key_i}, key = cnt<<12 | (4095-i)
//             (exactly replicates lax.top_k's (count desc, index asc) order)
//   scatter : rank<K -> new_xyz + sel[rank]=i
//   gatherF : out_feat[b][k][c] = points[b][c][sel[k]]  (coalesced writes)

#define BN 4
#define NPTS 4096
#define ND 64
#define KSEL 2048
#define R2 0.0025f   // RADIUS^2
#define M2 0.0004f   // MIN_RADIUS^2

#define IPT 4         // i-points per thread
#define ITILES 4      // NPTS / (256*IPT)
#define JC 32         // j-chunks
#define JCH 128       // NPTS / JC

__global__ __launch_bounds__(256) void prep_kernel(
        const float* __restrict__ xyz, float4* __restrict__ pts4,
        int* __restrict__ counts, int* __restrict__ ranks) {
    int tid = blockIdx.x * 256 + threadIdx.x;   // 0 .. B*N-1
    int b = tid >> 12, i = tid & (NPTS - 1);
    const float* base = xyz + (size_t)b * 3 * NPTS;
    float x = base[i], y = base[NPTS + i], z = base[2 * NPTS + i];
    // sq = (x*x + y*y) + z*z, no FMA contraction (bit-match numpy)
    float sq = __fadd_rn(__fadd_rn(__fmul_rn(x, x), __fmul_rn(y, y)),
                         __fmul_rn(z, z));
    pts4[tid] = make_float4(x, y, z, sq);
    counts[tid] = 0;
    ranks[tid] = 0;
}

__global__ __launch_bounds__(256) void count_kernel(
        const float4* __restrict__ pts4, int* __restrict__ counts) {
    __shared__ float4 sj[JCH];
    const int jc = blockIdx.x & (JC - 1);
    const int it = (blockIdx.x >> 5) & (ITILES - 1);
    const int b  = blockIdx.x >> 7;
    const float4* pb = pts4 + b * NPTS;

    if (threadIdx.x < JCH) sj[threadIdx.x] = pb[jc * JCH + threadIdx.x];

    const int ibase = it * 1024 + threadIdx.x;
    float4 mi[IPT];
    #pragma unroll
    for (int k = 0; k < IPT; ++k) mi[k] = pb[ibase + k * 256];
    __syncthreads();

    int cnt[IPT] = {0, 0, 0, 0};
    #pragma unroll 2
    for (int j = 0; j < JCH; ++j) {
        float4 p = sj[j];
        #pragma unroll
        for (int k = 0; k < IPT; ++k) {
            float dot = __fadd_rn(__fadd_rn(__fmul_rn(mi[k].x, p.x),
                                            __fmul_rn(mi[k].y, p.y)),
                                  __fmul_rn(mi[k].z, p.z));
            float d2 = __fsub_rn(__fadd_rn(mi[k].w, p.w), __fmul_rn(2.0f, dot));
            cnt[k] += (d2 < R2 && d2 > M2) ? 1 : 0;
        }
    }
    #pragma unroll
    for (int k = 0; k < IPT; ++k)
        atomicAdd(&counts[b * NPTS + ibase + k * 256], cnt[k]);
}

__global__ __launch_bounds__(256) void rank_kernel(
        const int* __restrict__ counts, int* __restrict__ ranks) {
    __shared__ int skey[JCH];
    const int jc = blockIdx.x & (JC - 1);
    const int it = (blockIdx.x >> 5) & (ITILES - 1);
    const int b  = blockIdx.x >> 7;
    const int* cb = counts + b * NPTS;

    if (threadIdx.x < JCH) {
        int j = jc * JCH + threadIdx.x;
        skey[threadIdx.x] = (cb[j] << 12) | (NPTS - 1 - j);
    }
    const int ibase = it * 1024 + threadIdx.x;
    int ki[IPT];
    #pragma unroll
    for (int k = 0; k < IPT; ++k) {
        int i = ibase + k * 256;
        ki[k] = (cb[i] << 12) | (NPTS - 1 - i);
    }
    __syncthreads();

    int r[IPT] = {0, 0, 0, 0};
    #pragma unroll 2
    for (int j = 0; j < JCH; ++j) {
        int kj = skey[j];
        #pragma unroll
        for (int k = 0; k < IPT; ++k) r[k] += (kj > ki[k]) ? 1 : 0;
    }
    #pragma unroll
    for (int k = 0; k < IPT; ++k)
        atomicAdd(&ranks[b * NPTS + ibase + k * 256], r[k]);
}

__global__ __launch_bounds__(256) void scatter_kernel(
        const float4* __restrict__ pts4, const int* __restrict__ ranks,
        int* __restrict__ sel, float* __restrict__ out) {
    int tid = blockIdx.x * 256 + threadIdx.x;
    int b = tid >> 12, i = tid & (NPTS - 1);
    int r = ranks[tid];
    if (r < KSEL) {
        sel[b * KSEL + r] = i;
        float4 p = pts4[tid];
        float* o = out + (size_t)(b * KSEL + r) * 3;
        o[0] = p.x; o[1] = p.y; o[2] = p.z;
    }
}

__global__ __launch_bounds__(256) void gatherf_kernel(
        const float* __restrict__ points, const int* __restrict__ sel,
        float* __restrict__ out) {
    int flat = blockIdx.x * 256 + threadIdx.x;   // (b*K + k)*ND + c
    int c = flat & (ND - 1);
    int k = (flat >> 6) & (KSEL - 1);
    int b = flat >> 17;
    int i = sel[b * KSEL + k];
    out[(size_t)BN * KSEL * 3 + flat] =
        points[(size_t)(b * ND + c) * NPTS + i];
}

extern "C" void kernel_launch(void* const* d_in, const int* in_sizes, int n_in,
                              void* d_out, int out_size, void* d_ws, size_t ws_size,
                              hipStream_t stream) {
    const float* xyz    = (const float*)d_in[0];   // [B, 3, N, 1]
    const float* points = (const float*)d_in[1];   // [B, D, N, 1]
    float* out = (float*)d_out;

    char* ws = (char*)d_ws;
    float4* pts4 = (float4*)ws;                         // 256 KB
    int* counts  = (int*)(ws + 256 * 1024);             //  64 KB
    int* ranks   = (int*)(ws + 320 * 1024);             //  64 KB
    int* sel     = (int*)(ws + 384 * 1024);             //  32 KB

    prep_kernel<<<BN * NPTS / 256, 256, 0, stream>>>(xyz, pts4, counts, ranks);
    count_kernel<<<BN * ITILES * JC, 256, 0, stream>>>(pts4, counts);
    rank_kernel<<<BN * ITILES * JC, 256, 0, stream>>>(counts, ranks);
    scatter_kernel<<<BN * NPTS / 256, 256, 0, stream>>>(pts4, ranks, sel, out);
    gatherf_kernel<<<BN * KSEL * ND / 256, 256, 0, stream>>>(points, sel, out);
}

// Round 3
// 91.427 us; speedup vs baseline: 2.9848x; 1.0040x over previous
//
#include <hip/hip_runtime.h>

// PoolObj: ball-query (annulus) neighbor-count downsampling + gather.
// B=4, N=4096, D=64, K=2048. Out = concat(new_xyz [B,K,3], new_points [B,K,D]).
//
// 3 kernels, no atomics, no zero-init:
//   count_part  : partial annulus counts, j-split (32 chunks), disjoint writes
//   key         : sum partials -> key = cnt<<12 | (4095-i)
//                 (one uint compare == lax.top_k (count desc, index asc) order)
//   rank_gather : rank_i = #{j : key_j > key_i}; rank<K -> write xyz + all 64
//                 features from one block (coalesced reads, scattered writes)

#define BN 4
#define NPTS 4096
#define ND 64
#define KSEL 2048
#define R2 0.0025f   // RADIUS^2
#define M2 0.0004f   // MIN_RADIUS^2

#define IPT 4         // i-points per thread
#define ITILES 4      // NPTS / (256*IPT)
#define JC 32         // j-chunks
#define JCH 128       // NPTS / JC

// K1: grid = BN*ITILES*JC = 512 blocks.
__global__ __launch_bounds__(256) void count_part_kernel(
        const float* __restrict__ xyz, int* __restrict__ part) {
    __shared__ float4 sj[JCH];   // 2 KB
    const int jc = blockIdx.x & (JC - 1);
    const int it = (blockIdx.x >> 5) & (ITILES - 1);
    const int b  = blockIdx.x >> 7;
    const float* base = xyz + (size_t)b * 3 * NPTS;

    if (threadIdx.x < JCH) {
        int j = jc * JCH + threadIdx.x;
        float x = base[j], y = base[NPTS + j], z = base[2 * NPTS + j];
        // sq = (x*x + y*y) + z*z, no FMA contraction (bit-match numpy)
        float sq = __fadd_rn(__fadd_rn(__fmul_rn(x, x), __fmul_rn(y, y)),
                             __fmul_rn(z, z));
        sj[threadIdx.x] = make_float4(x, y, z, sq);
    }
    const int ibase = it * 1024 + threadIdx.x;
    float4 mi[IPT];
    #pragma unroll
    for (int k = 0; k < IPT; ++k) {
        int i = ibase + k * 256;
        float x = base[i], y = base[NPTS + i], z = base[2 * NPTS + i];
        float sq = __fadd_rn(__fadd_rn(__fmul_rn(x, x), __fmul_rn(y, y)),
                             __fmul_rn(z, z));
        mi[k] = make_float4(x, y, z, sq);
    }
    __syncthreads();

    int cnt[IPT] = {0, 0, 0, 0};
    #pragma unroll 4
    for (int j = 0; j < JCH; ++j) {
        float4 p = sj[j];
        #pragma unroll
        for (int k = 0; k < IPT; ++k) {
            float dot = __fadd_rn(__fadd_rn(__fmul_rn(mi[k].x, p.x),
                                            __fmul_rn(mi[k].y, p.y)),
                                  __fmul_rn(mi[k].z, p.z));
            float d2 = __fsub_rn(__fadd_rn(mi[k].w, p.w), __fmul_rn(2.0f, dot));
            cnt[k] += (d2 < R2 && d2 > M2) ? 1 : 0;
        }
    }
    int* pp = part + (size_t)((b * ITILES + it) * JC + jc) * 1024;
    #pragma unroll
    for (int k = 0; k < IPT; ++k) pp[threadIdx.x + k * 256] = cnt[k];
}

// K2: grid = BN*NPTS/256 = 64 blocks.
__global__ __launch_bounds__(256) void key_kernel(
        const int* __restrict__ part, int* __restrict__ key) {
    int tid = blockIdx.x * 256 + threadIdx.x;
    int b = tid >> 12, i = tid & (NPTS - 1);
    int it = i >> 10, local = i & 1023;
    const int* pp = part + (size_t)(b * ITILES + it) * JC * 1024 + local;
    int c = 0;
    #pragma unroll
    for (int jc = 0; jc < JC; ++jc) c += pp[jc * 1024];
    key[tid] = (c << 12) | (NPTS - 1 - i);
}

// K3: grid = BN*64 = 256 blocks; block owns 64 consecutive i.
__global__ __launch_bounds__(256) void rank_gather_kernel(
        const float* __restrict__ xyz, const float* __restrict__ points,
        const int* __restrict__ key, float* __restrict__ out) {
    __shared__ int skey[NPTS];    // 16 KB
    __shared__ int spr[4][64];
    __shared__ int srank[64];
    const int b     = blockIdx.x >> 6;
    const int tbase = (blockIdx.x & 63) * 64;
    const int* kb = key + b * NPTS;
    for (int idx = threadIdx.x; idx < NPTS; idx += 256) skey[idx] = kb[idx];
    __syncthreads();

    const int ii = threadIdx.x & 63;
    const int q  = threadIdx.x >> 6;     // 4 threads per point
    const int ki = skey[tbase + ii];
    int r = 0;
    #pragma unroll 8
    for (int j = q * 1024; j < q * 1024 + 1024; ++j)
        r += (skey[j] > ki) ? 1 : 0;
    spr[q][ii] = r;
    __syncthreads();

    if (threadIdx.x < 64) {
        int rank = spr[0][threadIdx.x] + spr[1][threadIdx.x] +
                   spr[2][threadIdx.x] + spr[3][threadIdx.x];
        srank[threadIdx.x] = rank;
        int i = tbase + threadIdx.x;
        if (rank < KSEL) {
            const float* xb = xyz + (size_t)b * 3 * NPTS;
            float* o = out + ((size_t)b * KSEL + rank) * 3;
            o[0] = xb[i]; o[1] = xb[NPTS + i]; o[2] = xb[2 * NPTS + i];
        }
    }
    __syncthreads();

    // features: wave q covers c = q, q+4, ...; lane ii -> point tbase+ii
    // (reads coalesced across lanes; 4B scattered writes land in L2)
    const int rank = srank[ii];
    float* ofeat = out + (size_t)BN * KSEL * 3;
    for (int c = q; c < ND; c += 4) {
        float v = points[((size_t)b * ND + c) * NPTS + tbase + ii];
        if (rank < KSEL) ofeat[((size_t)b * KSEL + rank) * ND + c] = v;
    }
}

extern "C" void kernel_launch(void* const* d_in, const int* in_sizes, int n_in,
                              void* d_out, int out_size, void* d_ws, size_t ws_size,
                              hipStream_t stream) {
    const float* xyz    = (const float*)d_in[0];   // [B, 3, N, 1]
    const float* points = (const float*)d_in[1];   // [B, D, N, 1]
    float* out = (float*)d_out;

    char* ws = (char*)d_ws;
    int* part = (int*)ws;                           // 2 MB
    int* key  = (int*)(ws + 2 * 1024 * 1024);       // 64 KB

    count_part_kernel<<<BN * ITILES * JC, 256, 0, stream>>>(xyz, part);
    key_kernel<<<BN * NPTS / 256, 256, 0, stream>>>(part, key);
    rank_gather_kernel<<<BN * 64, 256, 0, stream>>>(xyz, points, key, out);
}